// Round 11
// baseline (528.782 us; speedup 1.0000x reference)
//
#include <hip/hip_runtime.h>
#include <math.h>

typedef unsigned short u16;
typedef unsigned int u32;

#define NBATCH 16
#define NCH    256
#define NPIX   4096
#define NHEAD  4
#define HDIM   32
#define NMEM   4
#define HID    128
#define OC3    384
#define SCALE_Q 0.17677669529663687f

typedef __bf16 bf16x8 __attribute__((ext_vector_type(8)));
typedef float  f32x4  __attribute__((ext_vector_type(4)));

// native casts -> compiler emits v_cvt_pk_bf16_f32 (RNE)
__device__ __forceinline__ u16 bfb(float f){
  union { __bf16 h; u16 u; } x; x.h = (__bf16)f; return x.u;
}
__device__ __forceinline__ u32 pkbf2(float a, float b){
  union { __bf16 h[2]; u32 u; } x; x.h[0] = (__bf16)a; x.h[1] = (__bf16)b; return x.u;
}
// async global->LDS, 16B per lane (dest = uniform base + lane*16)
__device__ __forceinline__ void gload_lds16(const void* gp, void* lp){
  __builtin_amdgcn_global_load_lds(
      (const __attribute__((address_space(1))) unsigned int*)gp,
      (__attribute__((address_space(3))) unsigned int*)lp, 16, 0, 0);
}

// ---------------------------------------------------------------------------
// K0: pack wqb[o][c] = bf16(w_qkv*g_in), wob[c][e] = bf16(w_out);
//     + precompute memory-token ctx contribution; + zero per-b counters.
// ---------------------------------------------------------------------------
__global__ __launch_bounds__(256) void k_pack(const float* __restrict__ wqkv,
                                              const float* __restrict__ gin,
                                              const float* __restrict__ wout,
                                              const float* __restrict__ memkv,
                                              u16* __restrict__ wqb,
                                              u16* __restrict__ wob,
                                              float* __restrict__ ctxmem,
                                              float* __restrict__ zmem,
                                              u32* __restrict__ cnt)
{
  int i = blockIdx.x*256 + threadIdx.x;
  if (i < OC3*NCH){ int c = i & 255; wqb[i] = bfb(wqkv[i]*gin[c]); }
  else if (i < OC3*NCH + NCH*HID){ int j = i - OC3*NCH; wob[j] = bfb(wout[j]); }
  else {
    int j = i - (OC3*NCH + NCH*HID);
    if (j < 4096){
      int h = j>>10, d = (j>>5)&31, e = j&31;
      float s = 0.f;
      #pragma unroll
      for (int m=0;m<4;m++)
        s += __expf(memkv[(h*HDIM+d)*NMEM + m]) * memkv[512 + (h*HDIM+e)*NMEM + m];
      ctxmem[j] = s;
    } else if (j < 4224){
      int k = j - 4096; int h = k>>5, d = k&31;
      float s = 0.f;
      #pragma unroll
      for (int m=0;m<4;m++) s += __expf(memkv[(h*HDIM+d)*NMEM + m]);
      zmem[k] = s;
    } else if (j < 4240){
      cnt[j-4224] = 0;
    }
  }
}

// ---------------------------------------------------------------------------
// K1: R6-proven body (rms-norm + QKV GEMM + q-softmax + per-tile ctx
// partials) + NEW last-block-per-b tail: the 64th block for batch b
// re-reads the 64 slabs, normalizes (+mem tokens), writes bf16
// ctxn[b][h][e][d] — replaces the k_red kernel and the memset.
// ---------------------------------------------------------------------------
__global__ __launch_bounds__(512, 4) void k_qkvx(const float* __restrict__ x,
                                                 const u16* __restrict__ wqb,
                                                 u16* __restrict__ qt,
                                                 float* __restrict__ ctxp2,
                                                 const float* __restrict__ ctxmem,
                                                 const float* __restrict__ zmem,
                                                 u16* __restrict__ ctxn,
                                                 u32* __restrict__ cnt)
{
  __shared__ __align__(16) char smem[52480];
  float (*Xs)[64]   = (float(*)[64])smem;               // 16384 B (phase-1 only)
  u16*   Bx         = (u16*)(smem + 16384);             // 64*264 u16 = 33792 B
  float (*ssqp)[64] = (float(*)[64])(smem + 50176);     // 2048 B
  float* rl         = (float*)(smem + 52224);           // 256 B
  // post-K-loop overlays (Xs and Bx are dead after the K-loop):
  u16*   Ek         = (u16*)smem;                       // 18432 B
  u16*   Vv         = (u16*)(smem + 18432);             // 18432 B
  float (*psx)[64]  = (float(*)[64])(smem + 36864);     // 2048 B
  __shared__ int lflag;

  const int t = threadIdx.x, w = t>>6, lane = t&63;
  const int n0 = blockIdx.x*64, b = blockIdx.y;
  const int qw = lane>>4, rr = lane&15;

  // phase 1: stage x via global_load_lds, pack bf16-transposed into Bx,
  // per-n sum-of-squares in fp32
  {
    float ssq = 0.f;
    for (int s=0;s<4;++s){
      asm volatile("s_waitcnt lgkmcnt(0)" ::: "memory");
      const float* gp = x + ((size_t)b*NCH + s*64 + w*8 + (lane>>4))*NPIX + n0 + (lane&15)*4;
      gload_lds16(gp,                    &Xs[w*8 + 0][0]);
      gload_lds16(gp + (size_t)4*NPIX,   &Xs[w*8 + 4][0]);
      asm volatile("s_waitcnt vmcnt(0)" ::: "memory");
      u32 pk[4];
      #pragma unroll
      for (int q=0;q<4;q++){
        float v0 = Xs[w*8 + 2*q    ][lane];
        float v1 = Xs[w*8 + 2*q + 1][lane];
        ssq += v0*v0 + v1*v1;
        pk[q] = pkbf2(v0, v1);
      }
      *(int4*)&Bx[lane*264 + s*64 + w*8] = make_int4((int)pk[0],(int)pk[1],(int)pk[2],(int)pk[3]);
    }
    ssqp[w][lane] = ssq;
  }
  __syncthreads();                                       // B1
  if (t < 64){
    float s = 0.f;
    #pragma unroll
    for (int g=0;g<8;g++) s += ssqp[g][t];
    rl[t] = 16.0f / fmaxf(sqrtf(s), 1e-12f);
  }

  f32x4 acc[3][4];
  #pragma unroll
  for (int p=0;p<3;p++)
    #pragma unroll
    for (int nf=0;nf<4;nf++) acc[p][nf] = (f32x4){0.f,0.f,0.f,0.f};

  // barrier-free K-loop: A-frags from global (L2) with 1-iter prefetch
  const u16* aw = wqb + (size_t)(w*16 + rr)*NCH + qw*8;
  bf16x8 caf0 = *(const bf16x8*)(aw);
  bf16x8 caf1 = *(const bf16x8*)(aw + 128*NCH);
  bf16x8 caf2 = *(const bf16x8*)(aw + 256*NCH);
  #pragma unroll
  for (int c0=0; c0<NCH; c0+=32){
    bf16x8 bfr[4];
    #pragma unroll
    for (int nf=0;nf<4;nf++)
      bfr[nf] = *(const bf16x8*)&Bx[(nf*16+rr)*264 + c0 + qw*8];
    bf16x8 naf0 = caf0, naf1 = caf1, naf2 = caf2;
    if (c0 < NCH-32){
      naf0 = *(const bf16x8*)(aw + c0+32);
      naf1 = *(const bf16x8*)(aw + 128*NCH + c0+32);
      naf2 = *(const bf16x8*)(aw + 256*NCH + c0+32);
    }
    #pragma unroll
    for (int nf=0;nf<4;nf++){
      acc[0][nf] = __builtin_amdgcn_mfma_f32_16x16x32_bf16(caf0, bfr[nf], acc[0][nf], 0, 0, 0); // q: D[o][n]
      acc[1][nf] = __builtin_amdgcn_mfma_f32_16x16x32_bf16(bfr[nf], caf1, acc[1][nf], 0, 0, 0); // k: D[n][o]
      acc[2][nf] = __builtin_amdgcn_mfma_f32_16x16x32_bf16(bfr[nf], caf2, acc[2][nf], 0, 0, 0); // v: D[n][o]
    }
    caf0 = naf0; caf1 = naf1; caf2 = naf2;
  }

  __syncthreads();   // B2: rl visible; Bx/Xs dead -> Ek/Vv/psx overlays usable

  // ek / vv -> LDS [o][n] (stride 72), z[o] partial
  float zk = 0.f;
  #pragma unroll
  for (int nf=0;nf<4;nf++){
    const float4 rv4 = *(const float4*)&rl[nf*16 + qw*4];
    float e0 = __expf(acc[1][nf][0]*rv4.x);
    float e1 = __expf(acc[1][nf][1]*rv4.y);
    float e2 = __expf(acc[1][nf][2]*rv4.z);
    float e3 = __expf(acc[1][nf][3]*rv4.w);
    zk += e0+e1+e2+e3;
    *(int2*)&Ek[(w*16+rr)*72 + nf*16 + qw*4] =
        make_int2((int)pkbf2(e0,e1), (int)pkbf2(e2,e3));
    float v0 = acc[2][nf][0]*rv4.x, v1 = acc[2][nf][1]*rv4.y;
    float v2 = acc[2][nf][2]*rv4.z, v3 = acc[2][nf][3]*rv4.w;
    *(int2*)&Vv[(w*16+rr)*72 + nf*16 + qw*4] =
        make_int2((int)pkbf2(v0,v1), (int)pkbf2(v2,v3));
  }
  zk += __shfl_xor(zk, 16, 64);
  zk += __shfl_xor(zk, 32, 64);

  // q: rl-scale + softmax over head_dim (16 in-wave d + 16 partner)
  float qv[4][4], pm[4], ps[4];
  #pragma unroll
  for (int nf=0;nf<4;nf++){
    float rv = rl[nf*16 + rr];
    float m = -1e30f;
    #pragma unroll
    for (int r=0;r<4;r++){ qv[nf][r] = acc[0][nf][r]*rv; m = fmaxf(m, qv[nf][r]); }
    m = fmaxf(m, __shfl_xor(m, 16, 64));
    m = fmaxf(m, __shfl_xor(m, 32, 64));
    float s = 0.f;
    #pragma unroll
    for (int r=0;r<4;r++){ qv[nf][r] = __expf(qv[nf][r]-m); s += qv[nf][r]; }
    s += __shfl_xor(s, 16, 64);
    s += __shfl_xor(s, 32, 64);
    pm[nf] = m; ps[nf] = s;
  }
  if (lane < 16){
    #pragma unroll
    for (int nf=0;nf<4;nf++){ ssqp[w][nf*16+lane] = pm[nf]; psx[w][nf*16+lane] = ps[nf]; }
  }
  __syncthreads();   // B3: partner partials + Ek/Vv visible
  {
    const int pw = w^1;   // waves (2h, 2h+1) share head h
    u16* qbase = qt + ((size_t)b*NPIX + n0)*HID + w*16 + qw*4;
    #pragma unroll
    for (int nf=0;nf<4;nf++){
      float om = ssqp[pw][nf*16+rr], os = psx[pw][nf*16+rr];
      float M = fmaxf(pm[nf], om);
      float S = ps[nf]*__expf(pm[nf]-M) + os*__expf(om-M);
      float f = __expf(pm[nf]-M) * SCALE_Q / S;
      u32 lo = pkbf2(qv[nf][0]*f, qv[nf][1]*f);
      u32 hi = pkbf2(qv[nf][2]*f, qv[nf][3]*f);
      *(int2*)(qbase + (size_t)(nf*16+rr)*HID) = make_int2((int)lo,(int)hi);
    }
  }

  // ctx partial GEMM: wave w -> head h=w>>1, e-half eh=w&1
  {
    const int h = w>>1, eh = w&1;
    f32x4 pacc[2] = {(f32x4){0.f,0.f,0.f,0.f},(f32x4){0.f,0.f,0.f,0.f}};
    #pragma unroll
    for (int ks=0; ks<2; ks++){
      bf16x8 bv = *(const bf16x8*)&Vv[(h*32+eh*16+rr)*72 + ks*32 + qw*8];
      #pragma unroll
      for (int i=0;i<2;i++){
        bf16x8 ae = *(const bf16x8*)&Ek[(h*32+i*16+rr)*72 + ks*32 + qw*8];
        pacc[i] = __builtin_amdgcn_mfma_f32_16x16x32_bf16(ae, bv, pacc[i], 0, 0, 0);
      }
    }
    float* pb = ctxp2 + ((size_t)((b*64 + blockIdx.x)*4 + h))*1088;
    #pragma unroll
    for (int i=0;i<2;i++)
      #pragma unroll
      for (int reg=0;reg<4;reg++)
        pb[(i*16+qw*4+reg)*32 + eh*16 + rr] = pacc[i][reg];
    if (qw==0) pb[1024 + (w&1)*16 + rr] = zk;
  }

  // ---- last-block-per-b reduce tail (release/acquire via cnt[b]) ----
  __threadfence();
  __syncthreads();
  if (t == 0){
    u32 old = __hip_atomic_fetch_add(cnt + b, 1u, __ATOMIC_ACQ_REL,
                                     __HIP_MEMORY_SCOPE_AGENT);
    lflag = (old == 63);
  }
  __syncthreads();
  if (!lflag) return;
  __threadfence();

  float* rl2 = (float*)ssqp;                 // 128 floats (overlay, dead region)
  float (*zps)[128] = (float(*)[128])psx;    // 4x128 floats (overlay)
  const float* cb = ctxp2 + (size_t)(b*64)*4*1088;
  {
    int sg = t>>7, idx = t&127;
    int h = idx>>5, dd = idx&31;
    const float* pz = cb + (size_t)h*1088 + 1024 + dd;
    float zs = 0.f;
    #pragma unroll
    for (int s=0;s<16;s++) zs += pz[(size_t)(sg*16+s)*4*1088];
    zps[sg][idx] = zs;
  }
  __syncthreads();
  if (t < 128) rl2[t] = 1.0f/(zps[0][t]+zps[1][t]+zps[2][t]+zps[3][t]+zmem[t]);
  __syncthreads();
  #pragma unroll
  for (int uu=0; uu<2; ++uu){
    int u = t + uu*512;                      // 0..1023
    int h = u>>8, dd = (u>>3)&31, e0 = (u&7)*4;
    const float* pp = cb + (size_t)h*1088 + dd*32 + e0;
    const float* cm = ctxmem + h*1024 + dd*32 + e0;
    float4 s4 = make_float4(cm[0],cm[1],cm[2],cm[3]);
    #pragma unroll
    for (int s=0;s<64;s++){
      float4 v = *(const float4*)(pp + (size_t)s*4*1088);
      s4.x+=v.x; s4.y+=v.y; s4.z+=v.z; s4.w+=v.w;
    }
    float ri = rl2[h*32+dd];
    u16* cn = ctxn + (size_t)b*4096 + h*1024 + dd;
    cn[(e0+0)*32] = bfb(s4.x*ri);
    cn[(e0+1)*32] = bfb(s4.y*ri);
    cn[(e0+2)*32] = bfb(s4.z*ri);
    cn[(e0+3)*32] = bfb(s4.w*ri);
  }
}

// ---------------------------------------------------------------------------
// K2: out = rms_c( wob . (ctxn-PV) + b_out ) * g_out.
// PV A-fragments DIRECT from ctxn global (8KB/b, L2-hot) — no staging.
// Second GEMM SWAPPED (row = n) -> float4 out stores (R8-proven epilogue).
// ---------------------------------------------------------------------------
__global__ __launch_bounds__(256) void k_fout(const u16* __restrict__ qt,
                                              const u16* __restrict__ ctxn,
                                              const u16* __restrict__ wob,
                                              const float* __restrict__ bout,
                                              const float* __restrict__ gout,
                                              float* __restrict__ out)
{
  __shared__ u16 Ao[64*136];      // [n][e(hid)]
  __shared__ float ssql[4][64];
  const int t = threadIdx.x, w = t>>6, lane = t&63;
  const int n0 = blockIdx.x*64, b = blockIdx.y;
  const int qw = lane>>4, rr = lane&15;

  // PV MFMA: wave w owns n-frag w (n = w*16 + rr); A from ctxn[b][h][e][d]
  f32x4 pv[4][2];
  const u16* qp  = qt + ((size_t)b*NPIX + n0 + w*16 + rr)*HID;
  const u16* cnb = ctxn + (size_t)b*4096;
  #pragma unroll
  for (int h=0;h<4;h++){
    bf16x8 bq = *(const bf16x8*)(qp + h*32 + qw*8);
    #pragma unroll
    for (int ef=0;ef<2;ef++){
      bf16x8 af = *(const bf16x8*)(cnb + (size_t)(h*32 + ef*16 + rr)*32 + qw*8);
      f32x4 z = (f32x4){0.f,0.f,0.f,0.f};
      pv[h][ef] = __builtin_amdgcn_mfma_f32_16x16x32_bf16(af, bq, z, 0, 0, 0);
    }
  }
  // write ao -> Ao[n][e] (C-layout: col n = w*16+rr, rows e = qw*4+reg)
  #pragma unroll
  for (int h=0;h<4;h++)
    #pragma unroll
    for (int ef=0;ef<2;ef++){
      u32 lohi0 = pkbf2(pv[h][ef][0], pv[h][ef][1]);
      u32 lohi1 = pkbf2(pv[h][ef][2], pv[h][ef][3]);
      *(int2*)&Ao[(w*16+rr)*136 + h*32 + ef*16 + qw*4] = make_int2((int)lohi0,(int)lohi1);
    }
  __syncthreads();

  // w_out GEMM (SWAPPED): A = Ao rows n, B = wob rows c -> D row=n, col=c
  f32x4 acc[4][4];
  #pragma unroll
  for (int i=0;i<4;i++)
    #pragma unroll
    for (int j=0;j<4;j++) acc[i][j] = (f32x4){0.f,0.f,0.f,0.f};
  #pragma unroll
  for (int k0=0; k0<HID; k0+=32){
    bf16x8 af[4], bfr[4];
    #pragma unroll
    for (int mf=0;mf<4;mf++)
      af[mf] = *(const bf16x8*)&wob[(size_t)(w*64 + mf*16 + rr)*HID + k0 + qw*8];
    #pragma unroll
    for (int nf=0;nf<4;nf++)
      bfr[nf] = *(const bf16x8*)&Ao[(nf*16+rr)*136 + k0 + qw*8];
    #pragma unroll
    for (int mf=0;mf<4;mf++)
      #pragma unroll
      for (int nf=0;nf<4;nf++)
        acc[mf][nf] = __builtin_amdgcn_mfma_f32_16x16x32_bf16(bfr[nf], af[mf], acc[mf][nf], 0, 0, 0);
  }
  // layout: c = w*64+mf*16+rr (col), n = nf*16+qw*4+reg (row)
  float psq[4][4] = {{0.f}};
  #pragma unroll
  for (int mf=0;mf<4;mf++){
    float bb = bout[w*64+mf*16+rr];
    #pragma unroll
    for (int nf=0;nf<4;nf++)
      #pragma unroll
      for (int reg=0;reg<4;reg++){
        float v = acc[mf][nf][reg] + bb;
        acc[mf][nf][reg] = v;
        psq[nf][reg] += v*v;
      }
  }
  #pragma unroll
  for (int nf=0;nf<4;nf++)
    #pragma unroll
    for (int reg=0;reg<4;reg++){
      psq[nf][reg] += __shfl_xor(psq[nf][reg], 1, 64);
      psq[nf][reg] += __shfl_xor(psq[nf][reg], 2, 64);
      psq[nf][reg] += __shfl_xor(psq[nf][reg], 4, 64);
      psq[nf][reg] += __shfl_xor(psq[nf][reg], 8, 64);
    }
  if (rr==0){
    #pragma unroll
    for (int nf=0;nf<4;nf++)
      #pragma unroll
      for (int reg=0;reg<4;reg++)
        ssql[w][nf*16+qw*4+reg] = psq[nf][reg];
  }
  __syncthreads();
  float4 rv4[4];
  #pragma unroll
  for (int nf=0;nf<4;nf++){
    float4 s0 = *(const float4*)&ssql[0][nf*16+qw*4];
    float4 s1 = *(const float4*)&ssql[1][nf*16+qw*4];
    float4 s2 = *(const float4*)&ssql[2][nf*16+qw*4];
    float4 s3 = *(const float4*)&ssql[3][nf*16+qw*4];
    rv4[nf].x = 16.0f / fmaxf(sqrtf(s0.x+s1.x+s2.x+s3.x), 1e-12f);
    rv4[nf].y = 16.0f / fmaxf(sqrtf(s0.y+s1.y+s2.y+s3.y), 1e-12f);
    rv4[nf].z = 16.0f / fmaxf(sqrtf(s0.z+s1.z+s2.z+s3.z), 1e-12f);
    rv4[nf].w = 16.0f / fmaxf(sqrtf(s0.w+s1.w+s2.w+s3.w), 1e-12f);
  }
  #pragma unroll
  for (int mf=0;mf<4;mf++){
    float g = gout[w*64+mf*16+rr];
    float* po = out + ((size_t)(b*NCH + w*64+mf*16+rr))*NPIX + n0;
    #pragma unroll
    for (int nf=0;nf<4;nf++){
      float4 o4;
      o4.x = acc[mf][nf][0]*rv4[nf].x*g;
      o4.y = acc[mf][nf][1]*rv4[nf].y*g;
      o4.z = acc[mf][nf][2]*rv4[nf].z*g;
      o4.w = acc[mf][nf][3]*rv4[nf].w*g;
      *(float4*)(po + nf*16 + qw*4) = o4;
    }
  }
}

// ---------------------------------------------------------------------------
extern "C" void kernel_launch(void* const* d_in, const int* in_sizes, int n_in,
                              void* d_out, int out_size, void* d_ws, size_t ws_size,
                              hipStream_t stream)
{
  const float* x     = (const float*)d_in[0];
  const float* gin   = (const float*)d_in[1];
  const float* memkv = (const float*)d_in[2];
  const float* wqkv  = (const float*)d_in[3];
  const float* wout  = (const float*)d_in[4];
  const float* bout  = (const float*)d_in[5];
  const float* gout  = (const float*)d_in[6];
  float* out = (float*)d_out;

  char* ws = (char*)d_ws;
  u16*    qt     = (u16*)   (ws);                    // 16,777,216 ([b][n][o] bf16)
  float*  ctxp2  = (float*) (ws + 16777216);         // 17,825,792 (16*64*4*1088*4)
  u16*    ctxn   = (u16*)   (ws + 34603008);         //    131,072 (16*4096 bf16)
  float*  ctxmem = (float*) (ws + 34734080);         //     16,384
  float*  zmem   = (float*) (ws + 34750464);         //        512
  u32*    cnt    = (u32*)   (ws + 34750976);         //         64 (pad 256)
  u16*    wqb    = (u16*)   (ws + 34751232);         //    196,608
  u16*    wob    = (u16*)   (ws + 34947840);         //     65,536 -> total 35,013,376

  hipLaunchKernelGGL(k_pack, dim3(529),   dim3(256), 0, stream,
                     wqkv, gin, wout, memkv, wqb, wob, ctxmem, zmem, cnt);
  hipLaunchKernelGGL(k_qkvx, dim3(64,16), dim3(512), 0, stream,
                     x, wqb, qt, ctxp2, ctxmem, zmem, ctxn, cnt);
  hipLaunchKernelGGL(k_fout, dim3(64,16), dim3(256), 0, stream,
                     qt, ctxn, wob, bout, gout, out);
}

// Round 12
// 177.780 us; speedup vs baseline: 2.9744x; 2.9744x over previous
//
#include <hip/hip_runtime.h>
#include <math.h>

typedef unsigned short u16;
typedef unsigned int u32;

#define NBATCH 16
#define NCH    256
#define NPIX   4096
#define NHEAD  4
#define HDIM   32
#define NMEM   4
#define HID    128
#define OC3    384
#define SCALE_Q 0.17677669529663687f

typedef __bf16 bf16x8 __attribute__((ext_vector_type(8)));
typedef float  f32x4  __attribute__((ext_vector_type(4)));

// native casts -> compiler emits v_cvt_pk_bf16_f32 (RNE)
__device__ __forceinline__ u16 bfb(float f){
  union { __bf16 h; u16 u; } x; x.h = (__bf16)f; return x.u;
}
__device__ __forceinline__ u32 pkbf2(float a, float b){
  union { __bf16 h[2]; u32 u; } x; x.h[0] = (__bf16)a; x.h[1] = (__bf16)b; return x.u;
}
// async global->LDS, 16B per lane (dest = uniform base + lane*16)
__device__ __forceinline__ void gload_lds16(const void* gp, void* lp){
  __builtin_amdgcn_global_load_lds(
      (const __attribute__((address_space(1))) unsigned int*)gp,
      (__attribute__((address_space(3))) unsigned int*)lp, 16, 0, 0);
}

// ---------------------------------------------------------------------------
// K0: pack wqb[o][c] = bf16(w_qkv*g_in), wob[c][e] = bf16(w_out);
//     + precompute memory-token ctx contribution (b-independent).
// ---------------------------------------------------------------------------
__global__ __launch_bounds__(256) void k_pack(const float* __restrict__ wqkv,
                                              const float* __restrict__ gin,
                                              const float* __restrict__ wout,
                                              const float* __restrict__ memkv,
                                              u16* __restrict__ wqb,
                                              u16* __restrict__ wob,
                                              float* __restrict__ ctxmem,
                                              float* __restrict__ zmem)
{
  int i = blockIdx.x*256 + threadIdx.x;
  if (i < OC3*NCH){ int c = i & 255; wqb[i] = bfb(wqkv[i]*gin[c]); }
  else if (i < OC3*NCH + NCH*HID){ int j = i - OC3*NCH; wob[j] = bfb(wout[j]); }
  else {
    int j = i - (OC3*NCH + NCH*HID);
    if (j < 4096){
      int h = j>>10, d = (j>>5)&31, e = j&31;
      float s = 0.f;
      #pragma unroll
      for (int m=0;m<4;m++)
        s += __expf(memkv[(h*HDIM+d)*NMEM + m]) * memkv[512 + (h*HDIM+e)*NMEM + m];
      ctxmem[j] = s;
    } else if (j < 4224){
      int k = j - 4096; int h = k>>5, d = k&31;
      float s = 0.f;
      #pragma unroll
      for (int m=0;m<4;m++) s += __expf(memkv[(h*HDIM+d)*NMEM + m]);
      zmem[k] = s;
    }
  }
}

// ---------------------------------------------------------------------------
// K1 (R10-proven, verbatim): rms-norm + QKV GEMM + q-softmax + per-tile ctx
// partials (P + z) into ctxp2 slabs (plain vector stores).
// ---------------------------------------------------------------------------
__global__ __launch_bounds__(512, 4) void k_qkvx(const float* __restrict__ x,
                                                 const u16* __restrict__ wqb,
                                                 u16* __restrict__ qt,
                                                 float* __restrict__ ctxp2)
{
  __shared__ __align__(16) char smem[52480];
  float (*Xs)[64]   = (float(*)[64])smem;               // 16384 B (phase-1 only)
  u16*   Bx         = (u16*)(smem + 16384);             // 64*264 u16 = 33792 B
  float (*ssqp)[64] = (float(*)[64])(smem + 50176);     // 2048 B
  float* rl         = (float*)(smem + 52224);           // 256 B
  // post-K-loop overlays (Xs and Bx are dead after the K-loop):
  u16*   Ek         = (u16*)smem;                       // 18432 B
  u16*   Vv         = (u16*)(smem + 18432);             // 18432 B
  float (*psx)[64]  = (float(*)[64])(smem + 36864);     // 2048 B

  const int t = threadIdx.x, w = t>>6, lane = t&63;
  const int n0 = blockIdx.x*64, b = blockIdx.y;
  const int qw = lane>>4, rr = lane&15;

  // phase 1: stage x via global_load_lds, pack bf16-transposed into Bx,
  // per-n sum-of-squares in fp32
  {
    float ssq = 0.f;
    for (int s=0;s<4;++s){
      asm volatile("s_waitcnt lgkmcnt(0)" ::: "memory");
      const float* gp = x + ((size_t)b*NCH + s*64 + w*8 + (lane>>4))*NPIX + n0 + (lane&15)*4;
      gload_lds16(gp,                    &Xs[w*8 + 0][0]);
      gload_lds16(gp + (size_t)4*NPIX,   &Xs[w*8 + 4][0]);
      asm volatile("s_waitcnt vmcnt(0)" ::: "memory");
      u32 pk[4];
      #pragma unroll
      for (int q=0;q<4;q++){
        float v0 = Xs[w*8 + 2*q    ][lane];
        float v1 = Xs[w*8 + 2*q + 1][lane];
        ssq += v0*v0 + v1*v1;
        pk[q] = pkbf2(v0, v1);
      }
      *(int4*)&Bx[lane*264 + s*64 + w*8] = make_int4((int)pk[0],(int)pk[1],(int)pk[2],(int)pk[3]);
    }
    ssqp[w][lane] = ssq;
  }
  __syncthreads();                                       // B1
  if (t < 64){
    float s = 0.f;
    #pragma unroll
    for (int g=0;g<8;g++) s += ssqp[g][t];
    rl[t] = 16.0f / fmaxf(sqrtf(s), 1e-12f);
  }

  f32x4 acc[3][4];
  #pragma unroll
  for (int p=0;p<3;p++)
    #pragma unroll
    for (int nf=0;nf<4;nf++) acc[p][nf] = (f32x4){0.f,0.f,0.f,0.f};

  // barrier-free K-loop: A-frags from global (L2) with 1-iter prefetch
  const u16* aw = wqb + (size_t)(w*16 + rr)*NCH + qw*8;
  bf16x8 caf0 = *(const bf16x8*)(aw);
  bf16x8 caf1 = *(const bf16x8*)(aw + 128*NCH);
  bf16x8 caf2 = *(const bf16x8*)(aw + 256*NCH);
  #pragma unroll
  for (int c0=0; c0<NCH; c0+=32){
    bf16x8 bfr[4];
    #pragma unroll
    for (int nf=0;nf<4;nf++)
      bfr[nf] = *(const bf16x8*)&Bx[(nf*16+rr)*264 + c0 + qw*8];
    bf16x8 naf0 = caf0, naf1 = caf1, naf2 = caf2;
    if (c0 < NCH-32){
      naf0 = *(const bf16x8*)(aw + c0+32);
      naf1 = *(const bf16x8*)(aw + 128*NCH + c0+32);
      naf2 = *(const bf16x8*)(aw + 256*NCH + c0+32);
    }
    #pragma unroll
    for (int nf=0;nf<4;nf++){
      acc[0][nf] = __builtin_amdgcn_mfma_f32_16x16x32_bf16(caf0, bfr[nf], acc[0][nf], 0, 0, 0); // q: D[o][n]
      acc[1][nf] = __builtin_amdgcn_mfma_f32_16x16x32_bf16(bfr[nf], caf1, acc[1][nf], 0, 0, 0); // k: D[n][o]
      acc[2][nf] = __builtin_amdgcn_mfma_f32_16x16x32_bf16(bfr[nf], caf2, acc[2][nf], 0, 0, 0); // v: D[n][o]
    }
    caf0 = naf0; caf1 = naf1; caf2 = naf2;
  }

  __syncthreads();   // B2: rl visible; Bx/Xs dead -> Ek/Vv/psx overlays usable

  // ek / vv -> LDS [o][n] (stride 72), z[o] partial
  float zk = 0.f;
  #pragma unroll
  for (int nf=0;nf<4;nf++){
    const float4 rv4 = *(const float4*)&rl[nf*16 + qw*4];
    float e0 = __expf(acc[1][nf][0]*rv4.x);
    float e1 = __expf(acc[1][nf][1]*rv4.y);
    float e2 = __expf(acc[1][nf][2]*rv4.z);
    float e3 = __expf(acc[1][nf][3]*rv4.w);
    zk += e0+e1+e2+e3;
    *(int2*)&Ek[(w*16+rr)*72 + nf*16 + qw*4] =
        make_int2((int)pkbf2(e0,e1), (int)pkbf2(e2,e3));
    float v0 = acc[2][nf][0]*rv4.x, v1 = acc[2][nf][1]*rv4.y;
    float v2 = acc[2][nf][2]*rv4.z, v3 = acc[2][nf][3]*rv4.w;
    *(int2*)&Vv[(w*16+rr)*72 + nf*16 + qw*4] =
        make_int2((int)pkbf2(v0,v1), (int)pkbf2(v2,v3));
  }
  zk += __shfl_xor(zk, 16, 64);
  zk += __shfl_xor(zk, 32, 64);

  // q: rl-scale + softmax over head_dim (16 in-wave d + 16 partner)
  float qv[4][4], pm[4], ps[4];
  #pragma unroll
  for (int nf=0;nf<4;nf++){
    float rv = rl[nf*16 + rr];
    float m = -1e30f;
    #pragma unroll
    for (int r=0;r<4;r++){ qv[nf][r] = acc[0][nf][r]*rv; m = fmaxf(m, qv[nf][r]); }
    m = fmaxf(m, __shfl_xor(m, 16, 64));
    m = fmaxf(m, __shfl_xor(m, 32, 64));
    float s = 0.f;
    #pragma unroll
    for (int r=0;r<4;r++){ qv[nf][r] = __expf(qv[nf][r]-m); s += qv[nf][r]; }
    s += __shfl_xor(s, 16, 64);
    s += __shfl_xor(s, 32, 64);
    pm[nf] = m; ps[nf] = s;
  }
  if (lane < 16){
    #pragma unroll
    for (int nf=0;nf<4;nf++){ ssqp[w][nf*16+lane] = pm[nf]; psx[w][nf*16+lane] = ps[nf]; }
  }
  __syncthreads();   // B3: partner partials + Ek/Vv visible
  {
    const int pw = w^1;   // waves (2h, 2h+1) share head h
    u16* qbase = qt + ((size_t)b*NPIX + n0)*HID + w*16 + qw*4;
    #pragma unroll
    for (int nf=0;nf<4;nf++){
      float om = ssqp[pw][nf*16+rr], os = psx[pw][nf*16+rr];
      float M = fmaxf(pm[nf], om);
      float S = ps[nf]*__expf(pm[nf]-M) + os*__expf(om-M);
      float f = __expf(pm[nf]-M) * SCALE_Q / S;
      u32 lo = pkbf2(qv[nf][0]*f, qv[nf][1]*f);
      u32 hi = pkbf2(qv[nf][2]*f, qv[nf][3]*f);
      *(int2*)(qbase + (size_t)(nf*16+rr)*HID) = make_int2((int)lo,(int)hi);
    }
  }

  // ctx partial GEMM: wave w -> head h=w>>1, e-half eh=w&1
  {
    const int h = w>>1, eh = w&1;
    f32x4 pacc[2] = {(f32x4){0.f,0.f,0.f,0.f},(f32x4){0.f,0.f,0.f,0.f}};
    #pragma unroll
    for (int ks=0; ks<2; ks++){
      bf16x8 bv = *(const bf16x8*)&Vv[(h*32+eh*16+rr)*72 + ks*32 + qw*8];
      #pragma unroll
      for (int i=0;i<2;i++){
        bf16x8 ae = *(const bf16x8*)&Ek[(h*32+i*16+rr)*72 + ks*32 + qw*8];
        pacc[i] = __builtin_amdgcn_mfma_f32_16x16x32_bf16(ae, bv, pacc[i], 0, 0, 0);
      }
    }
    float* pb = ctxp2 + ((size_t)((b*64 + blockIdx.x)*4 + h))*1088;
    #pragma unroll
    for (int i=0;i<2;i++)
      #pragma unroll
      for (int reg=0;reg<4;reg++)
        pb[(i*16+qw*4+reg)*32 + eh*16 + rr] = pacc[i][reg];
    if (qw==0) pb[1024 + (w&1)*16 + rr] = zk;
  }
}

// ---------------------------------------------------------------------------
// K2: reduce per-tile partials + mem tokens -> normalized bf16
// ctxn[b][h*32+e][d] (ready as PV A-fragments). One block per (b,h),
// no atomics, no memset. 64-iter independent-load loop (R6-proven cost).
// ---------------------------------------------------------------------------
__global__ __launch_bounds__(256) void k_red(const float* __restrict__ ctxp2,
                                             const float* __restrict__ ctxmem,
                                             const float* __restrict__ zmem,
                                             u16* __restrict__ ctxn)
{
  const int bh = blockIdx.x, b = bh>>2, h = bh&3;
  const int t = threadIdx.x;
  const int d = t>>3, e0 = (t&7)*4;
  const float* base = ctxp2 + ((size_t)(b*64)*4 + h)*1088;
  float4 s4 = make_float4(0.f,0.f,0.f,0.f);
  float z = 0.f;
  #pragma unroll 8
  for (int s=0;s<64;s++){
    const float* pb = base + (size_t)s*4*1088;
    float4 v = *(const float4*)(pb + d*32 + e0);
    s4.x+=v.x; s4.y+=v.y; s4.z+=v.z; s4.w+=v.w;
    z += pb[1024 + d];
  }
  const float* cm = ctxmem + h*1024 + d*32 + e0;
  float ri = 1.0f/(z + zmem[h*32 + d]);
  u16* cn = ctxn + (size_t)b*4096 + h*1024 + d;
  cn[(e0+0)*32] = bfb((s4.x+cm[0])*ri);
  cn[(e0+1)*32] = bfb((s4.y+cm[1])*ri);
  cn[(e0+2)*32] = bfb((s4.z+cm[2])*ri);
  cn[(e0+3)*32] = bfb((s4.w+cm[3])*ri);
}

// ---------------------------------------------------------------------------
// K3 (R11-proven body): out = rms_c( wob . PV + b_out ) * g_out.
// PV A-fragments DIRECT from ctxn global (8KB/b, L2-hot) — no staging.
// Second GEMM SWAPPED (row = n) -> float4 out stores.
// ---------------------------------------------------------------------------
__global__ __launch_bounds__(256) void k_fout(const u16* __restrict__ qt,
                                              const u16* __restrict__ ctxn,
                                              const u16* __restrict__ wob,
                                              const float* __restrict__ bout,
                                              const float* __restrict__ gout,
                                              float* __restrict__ out)
{
  __shared__ u16 Ao[64*136];      // [n][e(hid)]
  __shared__ float ssql[4][64];
  const int t = threadIdx.x, w = t>>6, lane = t&63;
  const int n0 = blockIdx.x*64, b = blockIdx.y;
  const int qw = lane>>4, rr = lane&15;

  // PV MFMA: wave w owns n-frag w (n = w*16 + rr); A from ctxn[b][h*32+e][d]
  f32x4 pv[4][2];
  const u16* qp  = qt + ((size_t)b*NPIX + n0 + w*16 + rr)*HID;
  const u16* cnb = ctxn + (size_t)b*4096;
  #pragma unroll
  for (int h=0;h<4;h++){
    bf16x8 bq = *(const bf16x8*)(qp + h*32 + qw*8);
    #pragma unroll
    for (int ef=0;ef<2;ef++){
      bf16x8 af = *(const bf16x8*)(cnb + (size_t)(h*32 + ef*16 + rr)*32 + qw*8);
      f32x4 z = (f32x4){0.f,0.f,0.f,0.f};
      pv[h][ef] = __builtin_amdgcn_mfma_f32_16x16x32_bf16(af, bq, z, 0, 0, 0);
    }
  }
  // write ao -> Ao[n][e] (C-layout: col n = w*16+rr, rows e = qw*4+reg)
  #pragma unroll
  for (int h=0;h<4;h++)
    #pragma unroll
    for (int ef=0;ef<2;ef++){
      u32 lohi0 = pkbf2(pv[h][ef][0], pv[h][ef][1]);
      u32 lohi1 = pkbf2(pv[h][ef][2], pv[h][ef][3]);
      *(int2*)&Ao[(w*16+rr)*136 + h*32 + ef*16 + qw*4] = make_int2((int)lohi0,(int)lohi1);
    }
  __syncthreads();

  // w_out GEMM (SWAPPED): A = Ao rows n, B = wob rows c -> D row=n, col=c
  f32x4 acc[4][4];
  #pragma unroll
  for (int i=0;i<4;i++)
    #pragma unroll
    for (int j=0;j<4;j++) acc[i][j] = (f32x4){0.f,0.f,0.f,0.f};
  #pragma unroll
  for (int k0=0; k0<HID; k0+=32){
    bf16x8 af[4], bfr[4];
    #pragma unroll
    for (int mf=0;mf<4;mf++)
      af[mf] = *(const bf16x8*)&wob[(size_t)(w*64 + mf*16 + rr)*HID + k0 + qw*8];
    #pragma unroll
    for (int nf=0;nf<4;nf++)
      bfr[nf] = *(const bf16x8*)&Ao[(nf*16+rr)*136 + k0 + qw*8];
    #pragma unroll
    for (int mf=0;mf<4;mf++)
      #pragma unroll
      for (int nf=0;nf<4;nf++)
        acc[mf][nf] = __builtin_amdgcn_mfma_f32_16x16x32_bf16(bfr[nf], af[mf], acc[mf][nf], 0, 0, 0);
  }
  // layout: c = w*64+mf*16+rr (col), n = nf*16+qw*4+reg (row)
  float psq[4][4] = {{0.f}};
  #pragma unroll
  for (int mf=0;mf<4;mf++){
    float bb = bout[w*64+mf*16+rr];
    #pragma unroll
    for (int nf=0;nf<4;nf++)
      #pragma unroll
      for (int reg=0;reg<4;reg++){
        float v = acc[mf][nf][reg] + bb;
        acc[mf][nf][reg] = v;
        psq[nf][reg] += v*v;
      }
  }
  #pragma unroll
  for (int nf=0;nf<4;nf++)
    #pragma unroll
    for (int reg=0;reg<4;reg++){
      psq[nf][reg] += __shfl_xor(psq[nf][reg], 1, 64);
      psq[nf][reg] += __shfl_xor(psq[nf][reg], 2, 64);
      psq[nf][reg] += __shfl_xor(psq[nf][reg], 4, 64);
      psq[nf][reg] += __shfl_xor(psq[nf][reg], 8, 64);
    }
  if (rr==0){
    #pragma unroll
    for (int nf=0;nf<4;nf++)
      #pragma unroll
      for (int reg=0;reg<4;reg++)
        ssql[w][nf*16+qw*4+reg] = psq[nf][reg];
  }
  __syncthreads();
  float4 rv4[4];
  #pragma unroll
  for (int nf=0;nf<4;nf++){
    float4 s0 = *(const float4*)&ssql[0][nf*16+qw*4];
    float4 s1 = *(const float4*)&ssql[1][nf*16+qw*4];
    float4 s2 = *(const float4*)&ssql[2][nf*16+qw*4];
    float4 s3 = *(const float4*)&ssql[3][nf*16+qw*4];
    rv4[nf].x = 16.0f / fmaxf(sqrtf(s0.x+s1.x+s2.x+s3.x), 1e-12f);
    rv4[nf].y = 16.0f / fmaxf(sqrtf(s0.y+s1.y+s2.y+s3.y), 1e-12f);
    rv4[nf].z = 16.0f / fmaxf(sqrtf(s0.z+s1.z+s2.z+s3.z), 1e-12f);
    rv4[nf].w = 16.0f / fmaxf(sqrtf(s0.w+s1.w+s2.w+s3.w), 1e-12f);
  }
  #pragma unroll
  for (int mf=0;mf<4;mf++){
    float g = gout[w*64+mf*16+rr];
    float* po = out + ((size_t)(b*NCH + w*64+mf*16+rr))*NPIX + n0;
    #pragma unroll
    for (int nf=0;nf<4;nf++){
      float4 o4;
      o4.x = acc[mf][nf][0]*rv4[nf].x*g;
      o4.y = acc[mf][nf][1]*rv4[nf].y*g;
      o4.z = acc[mf][nf][2]*rv4[nf].z*g;
      o4.w = acc[mf][nf][3]*rv4[nf].w*g;
      *(float4*)(po + nf*16 + qw*4) = o4;
    }
  }
}

// ---------------------------------------------------------------------------
extern "C" void kernel_launch(void* const* d_in, const int* in_sizes, int n_in,
                              void* d_out, int out_size, void* d_ws, size_t ws_size,
                              hipStream_t stream)
{
  const float* x     = (const float*)d_in[0];
  const float* gin   = (const float*)d_in[1];
  const float* memkv = (const float*)d_in[2];
  const float* wqkv  = (const float*)d_in[3];
  const float* wout  = (const float*)d_in[4];
  const float* bout  = (const float*)d_in[5];
  const float* gout  = (const float*)d_in[6];
  float* out = (float*)d_out;

  char* ws = (char*)d_ws;
  u16*    qt     = (u16*)   (ws);                    // 16,777,216 ([b][n][o] bf16)
  float*  ctxp2  = (float*) (ws + 16777216);         // 17,825,792 (16*64*4*1088*4)
  u16*    ctxn   = (u16*)   (ws + 34603008);         //    131,072 (16*4096 bf16)
  float*  ctxmem = (float*) (ws + 34734080);         //     16,384
  float*  zmem   = (float*) (ws + 34750464);         //        512
  u16*    wqb    = (u16*)   (ws + 34750976);         //    196,608
  u16*    wob    = (u16*)   (ws + 34947584);         //     65,536 -> total 35,013,120

  hipLaunchKernelGGL(k_pack, dim3(529),   dim3(256), 0, stream,
                     wqkv, gin, wout, memkv, wqb, wob, ctxmem, zmem);
  hipLaunchKernelGGL(k_qkvx, dim3(64,16), dim3(512), 0, stream, x, wqb, qt, ctxp2);
  hipLaunchKernelGGL(k_red,  dim3(64),    dim3(256), 0, stream,
                     ctxp2, ctxmem, zmem, ctxn);
  hipLaunchKernelGGL(k_fout, dim3(64,16), dim3(256), 0, stream,
                     qt, ctxn, wob, bout, gout, out);
}